// Round 5
// baseline (303.669 us; speedup 1.0000x reference)
//
#include <hip/hip_runtime.h>
#include <hip/hip_bf16.h>
#include <stdint.h>

// Band-limited linear layer: y = x @ (mask*W)^T + bias
// x: [8192, 4096] f32, W: [4096, 4096] f32 (band |o-i|<=64), bias: [4096] f32.
//
// R5 = R4's traffic-optimal shell (FETCH+WRITE = 269 MB exactly minimal) with
// the W pipeline hoisted out of the main loop:
//  - prep kernel packs masked bf16 W into d_ws (2 MB) in MFMA B-fragment
//    order [cb][chunk][s][wn][nf][lane] -> one coalesced 16B/lane load per
//    fragment. Runs once per launch (~2 us); dedups the mask+cvt work that
//    R4 redid in all 64 row-blocks.
//  - main kernel: W fragments stream from the L2-resident packed array
//    (prefetched one chunk ahead, 16 VGPRs); LDS is A-only ping-pong (36 KB);
//    stage VALU drops ~5x (x cvt only). Grid/pacing/stores identical to R4:
//    barrier-free designs are falsified (R2/R3 blew WRITE 1.6-3.3x).

constexpr int MROWS = 8192;
constexpr int NFEAT = 4096;
constexpr int KFEAT = 4096;
constexpr int DBAND = 64;

constexpr int BM = 128;
constexpr int BN = 128;
constexpr int BK = 64;                      // K chunk per staging step
constexpr int NCH = (BN + 2 * DBAND) / BK;  // 4 chunks over the 256 slice
constexpr int LDSW = BK + 8;                // 72 shorts: +16B pad

// packed-W geometry: per (cb, chunk): 16 fragments (s*8 + wn*2 + nf), each
// 64 lanes x 16 B = 1024 B.  Total 32*4*16*1024 = 2 MiB.
constexpr int WFRAG_B   = 1024;
constexpr int WCHUNK_B  = 16 * WFRAG_B;     // 16384
constexpr int WCB_B     = NCH * WCHUNK_B;   // 65536
constexpr size_t WPACK_B = (size_t)32 * WCB_B;  // 2 MiB

using bf16x8 = __attribute__((ext_vector_type(8))) short;  // 8 bf16 = 4 VGPRs
using f32x4  = __attribute__((ext_vector_type(4))) float;

__device__ __forceinline__ uint32_t pk2(float a, float b) {
    float2 t; t.x = a; t.y = b;
    __hip_bfloat162 h = __float22bfloat162_rn(t);
    union { __hip_bfloat162 h; uint32_t u; } cv;
    cv.h = h;
    return cv.u;  // low 16 = a, high 16 = b
}

// ---------------- prep: pack masked bf16 W fragments into workspace --------
__global__ __launch_bounds__(512)
void pack_w_kernel(const float* __restrict__ w, short* __restrict__ pw)
{
    const int cb = blockIdx.x;     // 0..31
    const int c  = blockIdx.y;     // 0..3
    const int tid  = threadIdx.x;
    const int lane = tid & 63;
    const int q    = tid >> 6;     // 0..7 = wn*2 + nf
    const int wn = q >> 1;
    const int nf = q & 1;
    const int gn = cb * 128 + wn * 32 + nf * 16 + (lane & 15);  // output feature

    #pragma unroll
    for (int s = 0; s < 2; ++s) {
        const int gk0 = cb * 128 - DBAND + c * BK + s * 32 + (lane >> 4) * 8;
        float v[8];
        #pragma unroll
        for (int j = 0; j < 8; ++j) {
            const int gk = gk0 + j;
            const bool ok = ((unsigned)gk < (unsigned)KFEAT) &&
                            ((unsigned)(gk - gn + DBAND) <= (unsigned)(2 * DBAND));
            v[j] = ok ? w[(size_t)gn * KFEAT + gk] : 0.f;
        }
        uint4 pkt;
        pkt.x = pk2(v[0], v[1]); pkt.y = pk2(v[2], v[3]);
        pkt.z = pk2(v[4], v[5]); pkt.w = pk2(v[6], v[7]);
        char* dst = (char*)pw + (size_t)cb * WCB_B + (size_t)c * WCHUNK_B
                  + (size_t)(s * 8 + wn * 2 + nf) * WFRAG_B + lane * 16;
        *(uint4*)dst = pkt;
    }
}

// ---------------- main ------------------------------------------------------
__global__ __launch_bounds__(512)
void band_linear_kernel(const float* __restrict__ x,
                        const short* __restrict__ pw,
                        const float* __restrict__ bias,
                        float* __restrict__ y)
{
    // A-only ping-pong: 2 x 18432 B = 36864 B
    __shared__ __align__(16) short sA[2][BM * LDSW];

    const int tid  = threadIdx.x;
    const int lane = tid & 63;
    const int wave = tid >> 6;      // 0..7
    const int wm = wave >> 2;       // row half (64 rows)
    const int wn = wave & 3;        // col quarter (32 cols)

    const int cb = blockIdx.x;      // col block 0..31 (fastest: cohort pacing)
    const int rb = blockIdx.y;      // row block 0..63
    const int row0 = rb * BM;
    const int col0 = cb * BN;
    const int i0 = col0 - DBAND;    // first global input index of the K-slice

    // A staging map: thread t -> tile row t>>2, 16-float span (t&3)*16
    const int srow = tid >> 2;           // 0..127
    const int koff = (tid & 3) * 16;     // 0,16,32,48
    const float* xsrc = x + (size_t)(row0 + srow) * KFEAT + koff;

    // W fragment base for this wave/lane (nf*1024 + c/s offsets added at use)
    const char* wfb = (const char*)pw + (size_t)cb * WCB_B
                    + (size_t)wn * (2 * WFRAG_B) + lane * 16;

    f32x4 acc[4][2];
    #pragma unroll
    for (int i = 0; i < 4; ++i)
        #pragma unroll
        for (int j = 0; j < 2; ++j)
            acc[i][j] = (f32x4){0.f, 0.f, 0.f, 0.f};

    float4 px[4];            // x prefetch (16 VGPRs)
    bf16x8 wf[2][2], wfn[2][2];  // W fragments [s][nf]: current + next chunk

    // uniform valid-chunk range (band edges are 64-aligned)
    int ch = (cb == 0) ? 1 : 0;
    const int che = (cb == (NFEAT / BN - 1)) ? (NCH - 1) : NCH;

    auto loadX = [&](int kc) {
        const int kb = i0 + kc * BK;
        #pragma unroll
        for (int g = 0; g < 4; ++g)
            px[g] = *(const float4*)(xsrc + kb + g * 4);
    };
    auto loadW = [&](int kc, bf16x8 out[2][2]) {
        #pragma unroll
        for (int s = 0; s < 2; ++s)
            #pragma unroll
            for (int nf = 0; nf < 2; ++nf)
                out[s][nf] = *(const bf16x8*)(wfb + (size_t)kc * WCHUNK_B
                                              + s * (8 * WFRAG_B) + nf * WFRAG_B);
    };
    auto stageA = [&](int pp) {   // cvt px -> bf16, write 32 B to LDS
        uint4 pa0, pa1;
        pa0.x = pk2(px[0].x, px[0].y);  pa0.y = pk2(px[0].z, px[0].w);
        pa0.z = pk2(px[1].x, px[1].y);  pa0.w = pk2(px[1].z, px[1].w);
        pa1.x = pk2(px[2].x, px[2].y);  pa1.y = pk2(px[2].z, px[2].w);
        pa1.z = pk2(px[3].x, px[3].y);  pa1.w = pk2(px[3].z, px[3].w);
        *(uint4*)&sA[pp][srow * LDSW + koff]     = pa0;
        *(uint4*)&sA[pp][srow * LDSW + koff + 8] = pa1;
    };

    // ---- prologue: chunk ch staged to buf0; W(ch) in regs; x(ch+1) in flight
    loadX(ch);
    loadW(ch, wf);
    stageA(0);
    if (ch + 1 < che) loadX(ch + 1);
    __syncthreads();

    int p = 0;
    while (true) {
        const bool more1 = (ch + 1) < che;
        const bool more2 = (ch + 2) < che;

        if (more1) {
            loadW(ch + 1, wfn);   // global issue first (needed next phase)
            stageA(p ^ 1);        // consumes px(ch+1); barrier last phase covers buffer
        }
        if (more2) loadX(ch + 2);

        // ---- MFMA chunk ch from sA[p] + wf: 2 k-steps, 4x2 grid per wave
        #pragma unroll
        for (int s = 0; s < 2; ++s) {
            bf16x8 af[4];
            #pragma unroll
            for (int mf = 0; mf < 4; ++mf) {
                const int r = wm * 64 + mf * 16 + (lane & 15);
                af[mf] = *(const bf16x8*)&sA[p][r * LDSW + s * 32 + (lane >> 4) * 8];
            }
            #pragma unroll
            for (int mf = 0; mf < 4; ++mf)
                #pragma unroll
                for (int nf = 0; nf < 2; ++nf)
                    acc[mf][nf] = __builtin_amdgcn_mfma_f32_16x16x32_bf16(
                        af[mf], wf[s][nf], acc[mf][nf], 0, 0, 0);
        }

        if (!more1) break;
        __syncthreads();          // one barrier per chunk
        #pragma unroll
        for (int s = 0; s < 2; ++s)
            #pragma unroll
            for (int nf = 0; nf < 2; ++nf)
                wf[s][nf] = wfn[s][nf];
        ++ch;
        p ^= 1;
    }

    // ---- epilogue: C/D layout col=lane&15, row=(lane>>4)*4+reg (as R1/R4)
    const int lquad = lane >> 4;
    const int lcol  = lane & 15;
    #pragma unroll
    for (int nf = 0; nf < 2; ++nf) {
        const int gc = col0 + wn * 32 + nf * 16 + lcol;
        const float bv = bias[gc];
        #pragma unroll
        for (int mf = 0; mf < 4; ++mf) {
            const int gr = row0 + wm * 64 + mf * 16 + lquad * 4;
            float* dst = y + (size_t)gr * NFEAT + gc;
            #pragma unroll
            for (int r2 = 0; r2 < 4; ++r2)
                dst[(size_t)r2 * NFEAT] = acc[mf][nf][r2] + bv;
        }
    }
}

extern "C" void kernel_launch(void* const* d_in, const int* in_sizes, int n_in,
                              void* d_out, int out_size, void* d_ws, size_t ws_size,
                              hipStream_t stream) {
    const float* x    = (const float*)d_in[0];
    const float* w    = (const float*)d_in[1];
    const float* bias = (const float*)d_in[2];
    // d_in[3] (mask) unused: band condition applied algebraically in prep.
    float* y = (float*)d_out;
    short* pwk = (short*)d_ws;    // needs 2 MiB of workspace

    dim3 pgrid(32, NCH);          // 128 blocks
    pack_w_kernel<<<pgrid, 512, 0, stream>>>(w, pwk);

    dim3 grid(NFEAT / BN, MROWS / BM);  // 32 x 64 = 2048 blocks
    band_linear_kernel<<<grid, 512, 0, stream>>>(x, pwk, bias, y);
}